// Round 1
// 339.911 us; speedup vs baseline: 1.0251x; 1.0251x over previous
//
#include <hip/hip_runtime.h>
#include <hip/hip_bf16.h>

#define N_NODES 100000
#define N_EDGES 3200000
#define NB 391                         // ceil(100000/256) buckets of 256 nodes
#define NBP 400                        // padded
#define CAP 9216                       // fixed bucket capacity: mean 8184 + 11.4 sigma
#define PCAP 20480                     // padded-layout ints per bucket (mean ~16.6K + 23 sigma)
#define ZNODE N_NODES                  // dummy node index -> all-zeros feature row
#define NTILES 6250                    // 100000 / 16
#define AROW 520                       // LDS A-tile row pitch in shorts (16B-aligned, bank-uniform)

typedef __attribute__((ext_vector_type(8))) short short8;
typedef __attribute__((ext_vector_type(4))) float floatx4;

__device__ __forceinline__ float bf2f(unsigned short u) {
    unsigned int x = ((unsigned int)u) << 16;
    return __builtin_bit_cast(float, x);
}
__device__ __forceinline__ unsigned short f2bf(float f) {
    unsigned int u = __builtin_bit_cast(unsigned int, f);
    unsigned int r = (u + 0x7FFFu + ((u >> 16) & 1u)) >> 16;
    return (unsigned short)r;
}

// ============ bucketed sort by segment (dst*8+t) -> padded node-major layout ============

__global__ __launch_bounds__(512) void k_init(int* __restrict__ cursor) {
    int tid = threadIdx.x;
    if (tid < NB) cursor[tid] = tid * CAP;
}

// single-pass: per-edge (bucket, word, local ofs) held in registers across the barrier
__global__ __launch_bounds__(1024) void k_bscatter(const int* __restrict__ ei,
                                                   const int* __restrict__ ti,
                                                   int* __restrict__ cursor,
                                                   unsigned int* __restrict__ words) {
    __shared__ int h[NBP];
    __shared__ int bb[NBP];
    int tid = threadIdx.x;
    if (tid < NBP) h[tid] = 0;
    __syncthreads();
    int base = blockIdx.x * 4096;
    int breg[4], ofs[4];
    unsigned wreg[4];
#pragma unroll
    for (int i = 0; i < 4; ++i) {
        int e = base + i * 1024 + tid;
        bool v = e < N_EDGES;
        int dst = v ? ei[N_EDGES + e] : 0;
        int src = v ? ei[e] : 0;
        int tt  = v ? ti[e] : 0;
        int b = dst >> 8;
        breg[i] = v ? b : -1;
        wreg[i] = ((unsigned)src << 11) | ((unsigned)(dst & 255) << 3) | (unsigned)tt;
        ofs[i] = v ? atomicAdd(&h[b], 1) : 0;
    }
    __syncthreads();
    if (tid < NB) {
        int c = h[tid];
        bb[tid] = c ? atomicAdd(&cursor[tid], c) : 0;
    }
    __syncthreads();
#pragma unroll
    for (int i = 0; i < 4; ++i)
        if (breg[i] >= 0) words[bb[breg[i]] + ofs[i]] = wreg[i];
}

// per-bucket: histogram -> per-node padded maxlen -> zero-fill -> scatter into
// gid_pad[node][k][t] (t fastest). Pad slots hold ZNODE (zeros row). Emits
// node_pm[n] = (pbase, maxlen_padded).
__global__ __launch_bounds__(1024) void k_lsort(const int* __restrict__ cursor,
                                                const unsigned int* __restrict__ words,
                                                int2* __restrict__ node_pm,
                                                int* __restrict__ gid_pad) {
    __shared__ int h[2048];
    __shared__ int ps[1024];
    __shared__ int nb[256];
    int tid = threadIdx.x;
    int b = blockIdx.x;
    int rb = b * CAP, re = cursor[b];
    h[tid] = 0; h[tid + 1024] = 0;
    __syncthreads();
    unsigned wreg[9];
    int ofs[9];
#pragma unroll
    for (int i = 0; i < 9; ++i) {
        int e = rb + i * 1024 + tid;
        bool v = e < re;
        unsigned w = v ? words[e] : 0u;
        wreg[i] = w;
        ofs[i] = v ? atomicAdd(&h[w & 2047u], 1) : -1;
    }
    __syncthreads();
    // per-node padded region size in ints: align2(maxlen) * 8
    int sz = 0;
    if (tid < 256) {
        int m = 0;
#pragma unroll
        for (int t = 0; t < 8; ++t) { int c = h[tid * 8 + t]; m = c > m ? c : m; }
        m = (m + 1) & ~1;              // even maxlen -> k-pair loop needs no tail
        sz = m * 8;
    }
    ps[tid] = sz;
    __syncthreads();
    for (int off = 1; off < 1024; off <<= 1) {
        int t = (tid >= off) ? ps[tid - off] : 0;
        __syncthreads();
        ps[tid] += t;
        __syncthreads();
    }
    if (tid < 256) nb[tid] = ps[tid] - sz;
    __syncthreads();
    int bsz = ps[1023];
    int pbase = b * PCAP;
    for (int s = tid; s < bsz; s += 1024) gid_pad[pbase + s] = ZNODE;
    int gn = b * 256 + tid;
    if (tid < 256 && gn < N_NODES) node_pm[gn] = (int2){pbase + nb[tid], sz >> 3};
    __syncthreads();
#pragma unroll
    for (int i = 0; i < 9; ++i)
        if (ofs[i] >= 0) {
            unsigned w = wreg[i];
            int ls = (int)(w & 2047u);
            gid_pad[pbase + nb[ls >> 3] + ofs[i] * 8 + (ls & 7)] = (int)(w >> 11);
        }
}

// ---------------- prep kernels ----------------

// convert x -> bf16 (row ZNODE zeroed); also zero h1b's ZNODE row for conv2 gathers
__global__ void k_cvt(const float* __restrict__ x, unsigned short* __restrict__ xb,
                      unsigned short* __restrict__ h1b) {
    int i = blockIdx.x * 256 + threadIdx.x;
    if (i < N_NODES * 64) xb[i] = f2bf(x[i]);
    if (i < 64) {
        xb[(size_t)ZNODE * 64 + i] = 0;
        h1b[(size_t)ZNODE * 64 + i] = 0;
    }
}

// W[512][64] -> B-fragment order; Wssl[64][64] likewise
__global__ void k_wprep(const float* __restrict__ W1, const float* __restrict__ W2,
                        const float* __restrict__ Wssl,
                        unsigned short* __restrict__ Wf1, unsigned short* __restrict__ Wf2,
                        unsigned short* __restrict__ Wsf) {
    int i = blockIdx.x * 256 + threadIdx.x;
    if (i < 512 * 64) {
        int k = i >> 6, o = i & 63;
        int c = o >> 4, m = o & 15;
        int ks = k >> 5, q = (k >> 3) & 3, j = k & 7;
        int pos = (((c * 16 + ks) * 64) + (m + 16 * q)) * 8 + j;
        Wf1[pos] = f2bf(W1[i]);
        Wf2[pos] = f2bf(W2[i]);
    }
    if (i < 64 * 64) {
        int k = i >> 6, o = i & 63;
        int c = o >> 4, m = o & 15;
        int ks = k >> 5, q = (k >> 3) & 3, j = k & 7;
        int pos = (((c * 2 + ks) * 64) + (m + 16 * q)) * 8 + j;
        Wsf[pos] = f2bf(Wssl[i]);
    }
}

// ---------------- fused conv: padded dwordx4-gather agg -> LDS A-tile -> MFMA -> relu ----------------
// Gather lane map: (t-row tl = lane>>3) x (feature-quad fo = lane&7).
// Because the padded layout is t-fastest, each k-step covers one full k-row of
// 8 t-slots, and t is FIXED per lane -> each (t, feature) pair has exactly one
// owner lane: no cross-lane reduce, 8 f32 accumulators per lane, one 16B gather
// per lane per k-step (vs 8x4B before). Pad slots are ZNODE -> zero row, L1-hot.

__global__ __launch_bounds__(512) void k_fused(const int2* __restrict__ node_pm,
                                               const int* __restrict__ gid_pad,
                                               const unsigned short* __restrict__ xb,
                                               const unsigned short* __restrict__ Wf,
                                               const float* __restrict__ bias,
                                               unsigned short* __restrict__ out_bf,
                                               float* __restrict__ out_f32) {
    __shared__ __align__(16) unsigned short Atile[32 * AROW];   // 33280 B
    int tid = threadIdx.x;
    int wave = tid >> 6, lane = tid & 63;
    int node_base = blockIdx.x * 32;
    int tl = lane >> 3, fo = lane & 7;
    const uint4* xs = (const uint4*)xb;         // row gid -> uint4 index gid*8 + fo

    for (int i = 0; i < 4; ++i) {               // 4 nodes per wave
        int nl = wave * 4 + i;                  // 0..31
        int n = node_base + nl;
        int2 pm = node_pm[n];
        int pb = __builtin_amdgcn_readfirstlane(pm.x);
        int ml = __builtin_amdgcn_readfirstlane(pm.y);   // even
        const int* gp = gid_pad + pb + tl;      // this lane's t-column
        float acc[8] = {0.f, 0.f, 0.f, 0.f, 0.f, 0.f, 0.f, 0.f};
        for (int k = 0; k < ml; k += 2) {
            int g0 = gp[k * 8];
            int g1 = gp[k * 8 + 8];
            uint4 p0 = xs[((unsigned)g0 << 3) + fo];
            uint4 p1 = xs[((unsigned)g1 << 3) + fo];
            acc[0] += __builtin_bit_cast(float, p0.x << 16);
            acc[1] += __builtin_bit_cast(float, p0.x & 0xFFFF0000u);
            acc[2] += __builtin_bit_cast(float, p0.y << 16);
            acc[3] += __builtin_bit_cast(float, p0.y & 0xFFFF0000u);
            acc[4] += __builtin_bit_cast(float, p0.z << 16);
            acc[5] += __builtin_bit_cast(float, p0.z & 0xFFFF0000u);
            acc[6] += __builtin_bit_cast(float, p0.w << 16);
            acc[7] += __builtin_bit_cast(float, p0.w & 0xFFFF0000u);
            acc[0] += __builtin_bit_cast(float, p1.x << 16);
            acc[1] += __builtin_bit_cast(float, p1.x & 0xFFFF0000u);
            acc[2] += __builtin_bit_cast(float, p1.y << 16);
            acc[3] += __builtin_bit_cast(float, p1.y & 0xFFFF0000u);
            acc[4] += __builtin_bit_cast(float, p1.z << 16);
            acc[5] += __builtin_bit_cast(float, p1.z & 0xFFFF0000u);
            acc[6] += __builtin_bit_cast(float, p1.w << 16);
            acc[7] += __builtin_bit_cast(float, p1.w & 0xFFFF0000u);
        }
        // pack 8 f32 -> 8 bf16 via HW packed convert (RTNE, matches f2bf), one b128 store.
        // Lane owns features [tl*64 + fo*8, +8) of node nl's 512-wide A row.
        unsigned r0, r1, r2, r3;
        asm("v_cvt_pk_bf16_f32 %0, %1, %2" : "=v"(r0) : "v"(acc[0]), "v"(acc[1]));
        asm("v_cvt_pk_bf16_f32 %0, %1, %2" : "=v"(r1) : "v"(acc[2]), "v"(acc[3]));
        asm("v_cvt_pk_bf16_f32 %0, %1, %2" : "=v"(r2) : "v"(acc[4]), "v"(acc[5]));
        asm("v_cvt_pk_bf16_f32 %0, %1, %2" : "=v"(r3) : "v"(acc[6]), "v"(acc[7]));
        uint4 st;
        st.x = r0; st.y = r1; st.z = r2; st.w = r3;
        *(uint4*)(&Atile[nl * AROW + tl * 64 + fo * 8]) = st;
    }
    __syncthreads();

    // GEMM: wave -> (node-tile nt = wave>>2, col-tile c = wave&3), 16 MFMA
    int nt = wave >> 2, c = wave & 3;
    int m = lane & 15, q = lane >> 4;
    floatx4 acc = (floatx4){0.f, 0.f, 0.f, 0.f};
    const short8* wf8 = (const short8*)Wf;
    const unsigned short* abase = &Atile[(nt * 16 + m) * AROW + q * 8];
#pragma unroll
    for (int ks = 0; ks < 16; ++ks) {
        short8 a = *(const short8*)(abase + ks * 32);
        short8 b = wf8[(c * 16 + ks) * 64 + lane];
        acc = __builtin_amdgcn_mfma_f32_16x16x32_bf16(a, b, acc, 0, 0, 0);
    }
    float bb = bias[c * 16 + m];
    int node0 = node_base + nt * 16;
#pragma unroll
    for (int i = 0; i < 4; ++i) {
        float v = acc[i] + bb;
        v = v > 0.f ? v : 0.f;
        int node = node0 + q * 4 + i;                 // C/D: row = quad*4 + reg
        size_t idx = (size_t)node * 64 + c * 16 + m;  //      col = lane&15
        if (out_bf)  out_bf[idx] = f2bf(v);
        if (out_f32) out_f32[idx] = v;
    }
}

// ---------------- SSL via MFMA: out = h2[N,64] @ Wssl[64,64] + bssl ----------------

__global__ __launch_bounds__(256) void k_sslm(const unsigned short* __restrict__ h2b,
                                              const unsigned short* __restrict__ Wsf,
                                              const float* __restrict__ bssl,
                                              float* __restrict__ out) {
    int wave = threadIdx.x >> 6, lane = threadIdx.x & 63;
    int tile = blockIdx.x * 4 + wave;
    if (tile >= NTILES) return;
    int m = lane & 15, q = lane >> 4;
    const unsigned short* arow = h2b + ((size_t)(tile * 16 + m)) * 64 + q * 8;
    floatx4 acc[4];
    for (int c = 0; c < 4; ++c) acc[c] = (floatx4){0.f, 0.f, 0.f, 0.f};
    const short8* wf8 = (const short8*)Wsf;
#pragma unroll
    for (int ks = 0; ks < 2; ++ks) {
        short8 a = *(const short8*)(arow + ks * 32);
#pragma unroll
        for (int c = 0; c < 4; ++c) {
            short8 b = wf8[(c * 2 + ks) * 64 + lane];
            acc[c] = __builtin_amdgcn_mfma_f32_16x16x32_bf16(a, b, acc[c], 0, 0, 0);
        }
    }
    int node0 = tile * 16;
#pragma unroll
    for (int c = 0; c < 4; ++c) {
        float bb = bssl[c * 16 + m];
#pragma unroll
        for (int i = 0; i < 4; ++i) {
            int node = node0 + q * 4 + i;
            out[(size_t)node * 64 + c * 16 + m] = acc[c][i] + bb;
        }
    }
}

// ---------------- launch ----------------

extern "C" void kernel_launch(void* const* d_in, const int* in_sizes, int n_in,
                              void* d_out, int out_size, void* d_ws, size_t ws_size,
                              hipStream_t stream) {
    const float* x    = (const float*)d_in[0];
    const int*   ei   = (const int*)d_in[1];   // [2,E]: row0 src, row1 dst
    const int*   ti   = (const int*)d_in[2];
    const float* W1   = (const float*)d_in[3];
    const float* b1   = (const float*)d_in[4];
    const float* W2   = (const float*)d_in[5];
    const float* b2   = (const float*)d_in[6];
    const float* Wssl = (const float*)d_in[7];
    const float* bssl = (const float*)d_in[8];
    float* out = (float*)d_out;

    char* w = (char*)d_ws;
    auto alloc = [&](size_t bytes) -> char* {
        char* p = w;
        w += (bytes + 255) & ~(size_t)255;
        return p;
    };
    int* cursor   = (int*)alloc((size_t)NBP * 4);
    unsigned int* words = (unsigned int*)alloc((size_t)NB * CAP * 4);
    int2* node_pm = (int2*)alloc((size_t)N_NODES * 8);
    int* gid_pad  = (int*)alloc((size_t)NB * PCAP * 4);
    unsigned short* xb  = (unsigned short*)alloc((size_t)(N_NODES + 1) * 64 * 2);
    unsigned short* h1b = (unsigned short*)alloc((size_t)(N_NODES + 1) * 64 * 2);
    unsigned short* h2b = (unsigned short*)alloc((size_t)N_NODES * 64 * 2);
    unsigned short* Wf1 = (unsigned short*)alloc((size_t)512 * 64 * 2);
    unsigned short* Wf2 = (unsigned short*)alloc((size_t)512 * 64 * 2);
    unsigned short* Wsf = (unsigned short*)alloc((size_t)64 * 64 * 2);

    k_init<<<1, 512, 0, stream>>>(cursor);
    k_bscatter<<<(N_EDGES + 4095) / 4096, 1024, 0, stream>>>(ei, ti, cursor, words);
    k_lsort<<<NB, 1024, 0, stream>>>(cursor, words, node_pm, gid_pad);
    k_cvt<<<(N_NODES * 64 + 255) / 256, 256, 0, stream>>>(x, xb, h1b);
    k_wprep<<<(512 * 64 + 255) / 256, 256, 0, stream>>>(W1, W2, Wssl, Wf1, Wf2, Wsf);

    // conv1 fused: agg(xb) + GEMM W1 + relu -> h1b (bf16)
    k_fused<<<N_NODES / 32, 512, 0, stream>>>(node_pm, gid_pad, xb, Wf1, b1, h1b, nullptr);
    // conv2 fused: agg(h1b) + GEMM W2 + relu -> d_out fp32 + h2b bf16
    k_fused<<<N_NODES / 32, 512, 0, stream>>>(node_pm, gid_pad, h1b, Wf2, b2, h2b, out);

    // ssl: h2 @ Wssl + bssl (MFMA)
    k_sslm<<<(NTILES + 3) / 4, 256, 0, stream>>>(h2b, Wsf, bssl, out + (size_t)N_NODES * 64);
}

// Round 2
// 323.720 us; speedup vs baseline: 1.0764x; 1.0500x over previous
//
#include <hip/hip_runtime.h>
#include <hip/hip_bf16.h>

#define N_NODES 100000
#define N_EDGES 3200000
#define NB 391                         // ceil(100000/256) buckets of 256 nodes
#define NBP 400                        // padded
#define CAP 9216                       // fixed bucket capacity: mean 8184 + 11.4 sigma
#define PCAP 20480                     // padded-layout ints per bucket (mean ~17.7K + 14 sigma)
#define ZNODE N_NODES                  // dummy node index -> all-zeros feature row
#define NTILES 6250                    // 100000 / 16
#define AROW 520                       // LDS A-tile row pitch in shorts (16B-aligned, bank-uniform)

typedef __attribute__((ext_vector_type(8))) short short8;
typedef __attribute__((ext_vector_type(4))) float floatx4;

__device__ __forceinline__ float bf2f(unsigned short u) {
    unsigned int x = ((unsigned int)u) << 16;
    return __builtin_bit_cast(float, x);
}
__device__ __forceinline__ unsigned short f2bf(float f) {
    unsigned int u = __builtin_bit_cast(unsigned int, f);
    unsigned int r = (u + 0x7FFFu + ((u >> 16) & 1u)) >> 16;
    return (unsigned short)r;
}

// ============ bucketed sort by segment (dst*8+t) -> padded node-major layout ============

// cursor[] starts memset-0; word region for bucket b is [b*CAP, b*CAP+count)
__global__ __launch_bounds__(1024) void k_bscatter(const int* __restrict__ ei,
                                                   const int* __restrict__ ti,
                                                   int* __restrict__ cursor,
                                                   unsigned int* __restrict__ words) {
    __shared__ int h[NBP];
    __shared__ int bb[NBP];
    int tid = threadIdx.x;
    if (tid < NBP) h[tid] = 0;
    __syncthreads();
    int base = blockIdx.x * 4096;
    int breg[4], ofs[4];
    unsigned wreg[4];
#pragma unroll
    for (int i = 0; i < 4; ++i) {
        int e = base + i * 1024 + tid;
        bool v = e < N_EDGES;
        int dst = v ? ei[N_EDGES + e] : 0;
        int src = v ? ei[e] : 0;
        int tt  = v ? ti[e] : 0;
        int b = dst >> 8;
        breg[i] = v ? b : -1;
        wreg[i] = ((unsigned)src << 11) | ((unsigned)(dst & 255) << 3) | (unsigned)tt;
        ofs[i] = v ? atomicAdd(&h[b], 1) : 0;
    }
    __syncthreads();
    if (tid < NB) {
        int c = h[tid];
        bb[tid] = c ? atomicAdd(&cursor[tid], c) : 0;
    }
    __syncthreads();
#pragma unroll
    for (int i = 0; i < 4; ++i)
        if (breg[i] >= 0) {
            int b = breg[i];
            words[b * CAP + bb[b] + ofs[i]] = wreg[i];
        }
}

// per-bucket: histogram -> per-node padded k-extent ml (mult of 4, >= 8) ->
// zero-fill -> scatter into gid_pad[node][t][k] (k fastest, per-t stride ml).
// Pad slots hold ZNODE (zeros row). Emits node_pm[n] = (pbase, ml).
__global__ __launch_bounds__(1024) void k_lsort(const int* __restrict__ cursor,
                                                const unsigned int* __restrict__ words,
                                                int2* __restrict__ node_pm,
                                                int* __restrict__ gid_pad) {
    __shared__ int h[2048];
    __shared__ int ps[1024];
    __shared__ int nb[256];
    __shared__ int s_ml[256];
    int tid = threadIdx.x;
    int b = blockIdx.x;
    int rb = b * CAP, re = rb + cursor[b];
    h[tid] = 0; h[tid + 1024] = 0;
    __syncthreads();
    unsigned wreg[9];
    int ofs[9];
#pragma unroll
    for (int i = 0; i < 9; ++i) {
        int e = rb + i * 1024 + tid;
        bool v = e < re;
        unsigned w = v ? words[e] : 0u;
        wreg[i] = w;
        ofs[i] = v ? atomicAdd(&h[w & 2047u], 1) : -1;
    }
    __syncthreads();
    // per-node padded region size in ints: ml * 8, ml = max(ceil4(maxcount), 8)
    int sz = 0;
    if (tid < 256) {
        int m = 0;
#pragma unroll
        for (int t = 0; t < 8; ++t) { int c = h[tid * 8 + t]; m = c > m ? c : m; }
        m = (m + 3) & ~3;
        if (m < 8) m = 8;
        s_ml[tid] = m;
        sz = m * 8;
    }
    ps[tid] = sz;
    __syncthreads();
    for (int off = 1; off < 1024; off <<= 1) {
        int t = (tid >= off) ? ps[tid - off] : 0;
        __syncthreads();
        ps[tid] += t;
        __syncthreads();
    }
    if (tid < 256) nb[tid] = ps[tid] - sz;
    __syncthreads();
    int bsz = ps[1023];
    int pbase = b * PCAP;
    for (int s = tid; s < bsz; s += 1024) gid_pad[pbase + s] = ZNODE;
    int gn = b * 256 + tid;
    if (tid < 256 && gn < N_NODES) node_pm[gn] = (int2){pbase + nb[tid], s_ml[tid]};
    __syncthreads();
#pragma unroll
    for (int i = 0; i < 9; ++i)
        if (ofs[i] >= 0) {
            unsigned w = wreg[i];
            int ls = (int)(w & 2047u);
            int nd = ls >> 3, t = ls & 7;
            gid_pad[pbase + nb[nd] + t * s_ml[nd] + ofs[i]] = (int)(w >> 11);
        }
}

// ---------------- prep: x -> bf16 (+ ZNODE zero rows) and weight fragment prep ----------------

__global__ void k_cvt(const float* __restrict__ x, unsigned short* __restrict__ xb,
                      unsigned short* __restrict__ h1b,
                      const float* __restrict__ W1, const float* __restrict__ W2,
                      const float* __restrict__ Wssl,
                      unsigned short* __restrict__ Wf1, unsigned short* __restrict__ Wf2,
                      unsigned short* __restrict__ Wsf) {
    int i = blockIdx.x * 256 + threadIdx.x;
    if (i < N_NODES * 64) xb[i] = f2bf(x[i]);
    if (i < 64) {
        xb[(size_t)ZNODE * 64 + i] = 0;
        h1b[(size_t)ZNODE * 64 + i] = 0;
    }
    if (i < 512 * 64) {
        int k = i >> 6, o = i & 63;
        int c = o >> 4, m = o & 15;
        int ks = k >> 5, q = (k >> 3) & 3, j = k & 7;
        int pos = (((c * 16 + ks) * 64) + (m + 16 * q)) * 8 + j;
        Wf1[pos] = f2bf(W1[i]);
        Wf2[pos] = f2bf(W2[i]);
    }
    if (i < 64 * 64) {
        int k = i >> 6, o = i & 63;
        int c = o >> 4, m = o & 15;
        int ks = k >> 5, q = (k >> 3) & 3, j = k & 7;
        int pos = (((c * 2 + ks) * 64) + (m + 16 * q)) * 8 + j;
        Wsf[pos] = f2bf(Wssl[i]);
    }
}

// ---------------- fused conv: 8-deep pipelined gather agg -> LDS A-tile -> MFMA -> relu ----------------
// Lane map: (t-row tl = lane>>3) x (feature-quad fo = lane&7). gid layout is
// [node][t][k] (k fastest, stride ml per t), so a lane's next 8 gids are two
// dwordx4 loads, and 8 independent 16B gathers go in flight together.
// Pad slots are ZNODE -> zero row, L1-hot, unconditional add.

__device__ __forceinline__ void accum8(float* a, uint4 p) {
    a[0] += __builtin_bit_cast(float, p.x << 16);
    a[1] += __builtin_bit_cast(float, p.x & 0xFFFF0000u);
    a[2] += __builtin_bit_cast(float, p.y << 16);
    a[3] += __builtin_bit_cast(float, p.y & 0xFFFF0000u);
    a[4] += __builtin_bit_cast(float, p.z << 16);
    a[5] += __builtin_bit_cast(float, p.z & 0xFFFF0000u);
    a[6] += __builtin_bit_cast(float, p.w << 16);
    a[7] += __builtin_bit_cast(float, p.w & 0xFFFF0000u);
}

__global__ __launch_bounds__(512) void k_fused(const int2* __restrict__ node_pm,
                                               const int* __restrict__ gid_pad,
                                               const unsigned short* __restrict__ xb,
                                               const unsigned short* __restrict__ Wf,
                                               const float* __restrict__ bias,
                                               unsigned short* __restrict__ out_bf,
                                               float* __restrict__ out_f32) {
    __shared__ __align__(16) unsigned short Atile[32 * AROW];   // 33280 B
    int tid = threadIdx.x;
    int wave = tid >> 6, lane = tid & 63;
    int node_base = blockIdx.x * 32;
    int tl = lane >> 3, fo = lane & 7;
    const uint4* xs = (const uint4*)xb;         // row gid -> uint4 index gid*8 + fo

    int2 pm[4];
#pragma unroll
    for (int i = 0; i < 4; ++i) pm[i] = node_pm[node_base + wave * 4 + i];

#pragma unroll
    for (int i = 0; i < 4; ++i) {               // 4 nodes per wave
        int nl = wave * 4 + i;                  // 0..31
        int pb = __builtin_amdgcn_readfirstlane(pm[i].x);
        int ml = __builtin_amdgcn_readfirstlane(pm[i].y);   // mult of 4, >= 8
        const int* gp = gid_pad + pb + tl * ml; // this lane's t-column
        float acc[8] = {0.f, 0.f, 0.f, 0.f, 0.f, 0.f, 0.f, 0.f};
        int k = 0;
#pragma unroll 1
        for (; k + 8 <= ml; k += 8) {
            int4 ga = *(const int4*)(gp + k);
            int4 gb = *(const int4*)(gp + k + 4);
            uint4 p0 = xs[((unsigned)ga.x << 3) + fo];
            uint4 p1 = xs[((unsigned)ga.y << 3) + fo];
            uint4 p2 = xs[((unsigned)ga.z << 3) + fo];
            uint4 p3 = xs[((unsigned)ga.w << 3) + fo];
            uint4 p4 = xs[((unsigned)gb.x << 3) + fo];
            uint4 p5 = xs[((unsigned)gb.y << 3) + fo];
            uint4 p6 = xs[((unsigned)gb.z << 3) + fo];
            uint4 p7 = xs[((unsigned)gb.w << 3) + fo];
            accum8(acc, p0); accum8(acc, p1); accum8(acc, p2); accum8(acc, p3);
            accum8(acc, p4); accum8(acc, p5); accum8(acc, p6); accum8(acc, p7);
        }
        if (k < ml) {                           // 4-tail (ml % 8 == 4)
            int4 ga = *(const int4*)(gp + k);
            uint4 p0 = xs[((unsigned)ga.x << 3) + fo];
            uint4 p1 = xs[((unsigned)ga.y << 3) + fo];
            uint4 p2 = xs[((unsigned)ga.z << 3) + fo];
            uint4 p3 = xs[((unsigned)ga.w << 3) + fo];
            accum8(acc, p0); accum8(acc, p1); accum8(acc, p2); accum8(acc, p3);
        }
        // pack 8 f32 -> 8 bf16 via HW packed convert (RTNE), one b128 LDS store.
        // Lane owns features [tl*64 + fo*8, +8) of node nl's 512-wide A row.
        unsigned r0, r1, r2, r3;
        asm("v_cvt_pk_bf16_f32 %0, %1, %2" : "=v"(r0) : "v"(acc[0]), "v"(acc[1]));
        asm("v_cvt_pk_bf16_f32 %0, %1, %2" : "=v"(r1) : "v"(acc[2]), "v"(acc[3]));
        asm("v_cvt_pk_bf16_f32 %0, %1, %2" : "=v"(r2) : "v"(acc[4]), "v"(acc[5]));
        asm("v_cvt_pk_bf16_f32 %0, %1, %2" : "=v"(r3) : "v"(acc[6]), "v"(acc[7]));
        uint4 st;
        st.x = r0; st.y = r1; st.z = r2; st.w = r3;
        *(uint4*)(&Atile[nl * AROW + tl * 64 + fo * 8]) = st;
    }
    __syncthreads();

    // GEMM: wave -> (node-tile nt = wave>>2, col-tile c = wave&3), 16 MFMA
    int nt = wave >> 2, c = wave & 3;
    int m = lane & 15, q = lane >> 4;
    floatx4 acc = (floatx4){0.f, 0.f, 0.f, 0.f};
    const short8* wf8 = (const short8*)Wf;
    const unsigned short* abase = &Atile[(nt * 16 + m) * AROW + q * 8];
#pragma unroll
    for (int ks = 0; ks < 16; ++ks) {
        short8 a = *(const short8*)(abase + ks * 32);
        short8 b = wf8[(c * 16 + ks) * 64 + lane];
        acc = __builtin_amdgcn_mfma_f32_16x16x32_bf16(a, b, acc, 0, 0, 0);
    }
    float bb = bias[c * 16 + m];
    int node0 = node_base + nt * 16;
#pragma unroll
    for (int i = 0; i < 4; ++i) {
        float v = acc[i] + bb;
        v = v > 0.f ? v : 0.f;
        int node = node0 + q * 4 + i;                 // C/D: row = quad*4 + reg
        size_t idx = (size_t)node * 64 + c * 16 + m;  //      col = lane&15
        if (out_bf)  out_bf[idx] = f2bf(v);
        if (out_f32) out_f32[idx] = v;
    }
}

// ---------------- SSL via MFMA: out = h2[N,64] @ Wssl[64,64] + bssl ----------------

__global__ __launch_bounds__(256) void k_sslm(const unsigned short* __restrict__ h2b,
                                              const unsigned short* __restrict__ Wsf,
                                              const float* __restrict__ bssl,
                                              float* __restrict__ out) {
    int wave = threadIdx.x >> 6, lane = threadIdx.x & 63;
    int tile = blockIdx.x * 4 + wave;
    if (tile >= NTILES) return;
    int m = lane & 15, q = lane >> 4;
    const unsigned short* arow = h2b + ((size_t)(tile * 16 + m)) * 64 + q * 8;
    floatx4 acc[4];
    for (int c = 0; c < 4; ++c) acc[c] = (floatx4){0.f, 0.f, 0.f, 0.f};
    const short8* wf8 = (const short8*)Wsf;
#pragma unroll
    for (int ks = 0; ks < 2; ++ks) {
        short8 a = *(const short8*)(arow + ks * 32);
#pragma unroll
        for (int c = 0; c < 4; ++c) {
            short8 b = wf8[(c * 2 + ks) * 64 + lane];
            acc[c] = __builtin_amdgcn_mfma_f32_16x16x32_bf16(a, b, acc[c], 0, 0, 0);
        }
    }
    int node0 = tile * 16;
#pragma unroll
    for (int c = 0; c < 4; ++c) {
        float bb = bssl[c * 16 + m];
#pragma unroll
        for (int i = 0; i < 4; ++i) {
            int node = node0 + q * 4 + i;
            out[(size_t)node * 64 + c * 16 + m] = acc[c][i] + bb;
        }
    }
}

// ---------------- launch ----------------

extern "C" void kernel_launch(void* const* d_in, const int* in_sizes, int n_in,
                              void* d_out, int out_size, void* d_ws, size_t ws_size,
                              hipStream_t stream) {
    const float* x    = (const float*)d_in[0];
    const int*   ei   = (const int*)d_in[1];   // [2,E]: row0 src, row1 dst
    const int*   ti   = (const int*)d_in[2];
    const float* W1   = (const float*)d_in[3];
    const float* b1   = (const float*)d_in[4];
    const float* W2   = (const float*)d_in[5];
    const float* b2   = (const float*)d_in[6];
    const float* Wssl = (const float*)d_in[7];
    const float* bssl = (const float*)d_in[8];
    float* out = (float*)d_out;

    char* w = (char*)d_ws;
    auto alloc = [&](size_t bytes) -> char* {
        char* p = w;
        w += (bytes + 255) & ~(size_t)255;
        return p;
    };
    int* cursor   = (int*)alloc((size_t)NBP * 4);
    unsigned int* words = (unsigned int*)alloc((size_t)NB * CAP * 4);
    int2* node_pm = (int2*)alloc((size_t)N_NODES * 8);
    int* gid_pad  = (int*)alloc((size_t)NB * PCAP * 4);
    unsigned short* xb  = (unsigned short*)alloc((size_t)(N_NODES + 1) * 64 * 2);
    unsigned short* h1b = (unsigned short*)alloc((size_t)(N_NODES + 1) * 64 * 2);
    unsigned short* h2b = (unsigned short*)alloc((size_t)N_NODES * 64 * 2);
    unsigned short* Wf1 = (unsigned short*)alloc((size_t)512 * 64 * 2);
    unsigned short* Wf2 = (unsigned short*)alloc((size_t)512 * 64 * 2);
    unsigned short* Wsf = (unsigned short*)alloc((size_t)64 * 64 * 2);

    hipMemsetAsync(cursor, 0, (size_t)NBP * 4, stream);
    k_bscatter<<<(N_EDGES + 4095) / 4096, 1024, 0, stream>>>(ei, ti, cursor, words);
    k_lsort<<<NB, 1024, 0, stream>>>(cursor, words, node_pm, gid_pad);
    k_cvt<<<(N_NODES * 64 + 255) / 256, 256, 0, stream>>>(x, xb, h1b, W1, W2, Wssl,
                                                          Wf1, Wf2, Wsf);

    // conv1 fused: agg(xb) + GEMM W1 + relu -> h1b (bf16)
    k_fused<<<N_NODES / 32, 512, 0, stream>>>(node_pm, gid_pad, xb, Wf1, b1, h1b, nullptr);
    // conv2 fused: agg(h1b) + GEMM W2 + relu -> d_out fp32 + h2b bf16
    k_fused<<<N_NODES / 32, 512, 0, stream>>>(node_pm, gid_pad, h1b, Wf2, b2, h2b, out);

    // ssl: h2 @ Wssl + bssl (MFMA)
    k_sslm<<<(NTILES + 3) / 4, 256, 0, stream>>>(h2b, Wsf, bssl, out + (size_t)N_NODES * 64);
}

// Round 3
// 303.110 us; speedup vs baseline: 1.1496x; 1.0680x over previous
//
#include <hip/hip_runtime.h>
#include <hip/hip_bf16.h>

#define N_NODES 100000
#define N_EDGES 3200000
#define NB 391                         // ceil(100000/256) buckets of 256 nodes
#define NBP 400                        // padded
#define CAP 9216                       // fixed bucket capacity: mean 8184 + 11.4 sigma
#define PCAP 20480                     // padded-layout ints per bucket
#define ZNODE N_NODES                  // dummy node index -> all-zeros feature row
#define AROW 520                       // LDS A-tile row pitch in shorts (16B-aligned)
#define HROW 72                        // LDS h2-tile row pitch in shorts (SSL phase)

typedef __attribute__((ext_vector_type(8))) short short8;
typedef __attribute__((ext_vector_type(4))) float floatx4;
typedef __attribute__((ext_vector_type(2))) float f32x2;

__device__ __forceinline__ unsigned short f2bf(float f) {
    unsigned int u = __builtin_bit_cast(unsigned int, f);
    unsigned int r = (u + 0x7FFFu + ((u >> 16) & 1u)) >> 16;
    return (unsigned short)r;
}

// ============ bucketed sort by segment (dst*8+t) -> padded node-major layout ============
// cursor[] starts memset-0; word region for bucket b is [b*CAP, b*CAP+count).
// Also carries the independent prep work (x->bf16, weight fragment packing) so it
// overlaps with the atomic-heavy scatter instead of being a separate dispatch.
__global__ __launch_bounds__(1024) void k_bscatter(const int* __restrict__ ei,
                                                   const int* __restrict__ ti,
                                                   int* __restrict__ cursor,
                                                   unsigned int* __restrict__ words,
                                                   const float* __restrict__ x,
                                                   unsigned short* __restrict__ xb,
                                                   unsigned short* __restrict__ h1b,
                                                   const float* __restrict__ W1,
                                                   const float* __restrict__ W2,
                                                   const float* __restrict__ Wssl,
                                                   unsigned short* __restrict__ Wf1,
                                                   unsigned short* __restrict__ Wf2,
                                                   unsigned short* __restrict__ Wsf) {
    __shared__ int h[NBP];
    __shared__ int bb[NBP];
    int tid = threadIdx.x;
    if (tid < NBP) h[tid] = 0;
    __syncthreads();
    int base = blockIdx.x * 4096;
    int breg[4], ofs[4];
    unsigned wreg[4];
#pragma unroll
    for (int i = 0; i < 4; ++i) {
        int e = base + i * 1024 + tid;
        bool v = e < N_EDGES;
        int dst = v ? ei[N_EDGES + e] : 0;
        int src = v ? ei[e] : 0;
        int tt  = v ? ti[e] : 0;
        int b = dst >> 8;
        breg[i] = v ? b : -1;
        wreg[i] = ((unsigned)src << 11) | ((unsigned)(dst & 255) << 3) | (unsigned)tt;
        ofs[i] = v ? atomicAdd(&h[b], 1) : 0;
    }
    __syncthreads();
    if (tid < NB) {
        int c = h[tid];
        bb[tid] = c ? atomicAdd(&cursor[tid], c) : 0;
    }
    __syncthreads();
#pragma unroll
    for (int i = 0; i < 4; ++i)
        if (breg[i] >= 0) {
            int b = breg[i];
            words[b * CAP + bb[b] + ofs[i]] = wreg[i];
        }

    // ---- fused prep (independent outputs; no barrier needed) ----
    int gtid = blockIdx.x * 1024 + tid;          // 800768 threads
    size_t xo = (size_t)gtid * 8;                // 8 floats -> 8 bf16 per thread
    if (xo < (size_t)N_NODES * 64) {
        float4 f0 = *(const float4*)(x + xo);
        float4 f1 = *(const float4*)(x + xo + 4);
        unsigned r0, r1, r2, r3;
        asm("v_cvt_pk_bf16_f32 %0, %1, %2" : "=v"(r0) : "v"(f0.x), "v"(f0.y));
        asm("v_cvt_pk_bf16_f32 %0, %1, %2" : "=v"(r1) : "v"(f0.z), "v"(f0.w));
        asm("v_cvt_pk_bf16_f32 %0, %1, %2" : "=v"(r2) : "v"(f1.x), "v"(f1.y));
        asm("v_cvt_pk_bf16_f32 %0, %1, %2" : "=v"(r3) : "v"(f1.z), "v"(f1.w));
        uint4 st; st.x = r0; st.y = r1; st.z = r2; st.w = r3;
        *(uint4*)(xb + xo) = st;
    }
    if (gtid < 64) {
        xb[(size_t)ZNODE * 64 + gtid] = 0;
        h1b[(size_t)ZNODE * 64 + gtid] = 0;
    }
    if (gtid < 512 * 64) {
        int k = gtid >> 6, o = gtid & 63;
        int c = o >> 4, m = o & 15;
        int ks = k >> 5, q = (k >> 3) & 3, j = k & 7;
        int pos = (((c * 16 + ks) * 64) + (m + 16 * q)) * 8 + j;
        Wf1[pos] = f2bf(W1[gtid]);
        Wf2[pos] = f2bf(W2[gtid]);
    }
    if (gtid < 64 * 64) {
        int k = gtid >> 6, o = gtid & 63;
        int c = o >> 4, m = o & 15;
        int ks = k >> 5, q = (k >> 3) & 3, j = k & 7;
        int pos = (((c * 2 + ks) * 64) + (m + 16 * q)) * 8 + j;
        Wsf[pos] = f2bf(Wssl[gtid]);
    }
}

// per-bucket: histogram -> per-node padded k-extent ml (mult of 4, >= 8) ->
// shfl-scan (2 barriers) -> zero-fill -> scatter into gid_pad[node][t][k]
// (k fastest, per-t stride ml). Pad slots hold ZNODE. node_pm[n] = (pbase, ml).
__global__ __launch_bounds__(1024) void k_lsort(const int* __restrict__ cursor,
                                                const unsigned int* __restrict__ words,
                                                int2* __restrict__ node_pm,
                                                int* __restrict__ gid_pad) {
    __shared__ int h[2048];
    __shared__ int nb[256];
    __shared__ int s_ml[256];
    __shared__ int wsum[4];
    int tid = threadIdx.x;
    int b = blockIdx.x;
    int rb = b * CAP, re = rb + cursor[b];
    h[tid] = 0; h[tid + 1024] = 0;
    __syncthreads();
    unsigned wreg[9];
    int ofs[9];
#pragma unroll
    for (int i = 0; i < 9; ++i) {
        int e = rb + i * 1024 + tid;
        bool v = e < re;
        unsigned w = v ? words[e] : 0u;
        wreg[i] = w;
        ofs[i] = v ? atomicAdd(&h[w & 2047u], 1) : -1;
    }
    __syncthreads();
    // per-node padded region size in ints: ml * 8, ml = max(ceil4(maxcount), 8)
    int sz = 0;
    if (tid < 256) {
        int m = 0;
#pragma unroll
        for (int t = 0; t < 8; ++t) { int c = h[tid * 8 + t]; m = c > m ? c : m; }
        m = (m + 3) & ~3;
        if (m < 8) m = 8;
        s_ml[tid] = m;
        sz = m * 8;
    }
    // 64-lane shfl inclusive scan + 4-wave combine (replaces 20-barrier scan)
    int lane = tid & 63, wv = tid >> 6;
    int inc = sz;
#pragma unroll
    for (int off = 1; off < 64; off <<= 1) {
        int t = __shfl_up(inc, off, 64);
        if (lane >= off) inc += t;
    }
    if (tid < 256 && lane == 63) wsum[wv] = inc;
    __syncthreads();
    int bsz = wsum[0] + wsum[1] + wsum[2] + wsum[3];
    if (tid < 256) {
        int basec = 0;
        for (int w = 0; w < wv; ++w) basec += wsum[w];
        nb[tid] = basec + inc - sz;
    }
    int pbase = b * PCAP;
    for (int s = tid; s < bsz; s += 1024) gid_pad[pbase + s] = ZNODE;
    int gn = b * 256 + tid;
    if (tid < 256 && gn < N_NODES) node_pm[gn] = (int2){pbase + nb[tid], s_ml[tid]};
    __syncthreads();
#pragma unroll
    for (int i = 0; i < 9; ++i)
        if (ofs[i] >= 0) {
            unsigned w = wreg[i];
            int ls = (int)(w & 2047u);
            int nd = ls >> 3, t = ls & 7;
            gid_pad[pbase + nb[nd] + t * s_ml[nd] + ofs[i]] = (int)(w >> 11);
        }
}

// ---------------- fused conv: 16-deep pipelined gather agg -> LDS A-tile -> MFMA -> relu
// ---------------- (+ optional fused SSL GEMM using the block-resident h2 tile)
// Lane map: (t-row tl = lane>>3) x (feature-quad fo = lane&7). gid layout [node][t][k]
// (k fastest, stride ml). All 4 nodes' gid rows are loaded up front (8 dwordx4),
// then nodes are processed in pairs with 16 independent 16B gathers in flight.
// Pad slots are ZNODE -> zero row, L1-hot, unconditional add.

__device__ __forceinline__ void accumP(f32x2* a, uint4 p) {
    uint2 u;
    u.x = p.x << 16; u.y = p.x & 0xFFFF0000u;
    a[0] += __builtin_bit_cast(f32x2, u);
    u.x = p.y << 16; u.y = p.y & 0xFFFF0000u;
    a[1] += __builtin_bit_cast(f32x2, u);
    u.x = p.z << 16; u.y = p.z & 0xFFFF0000u;
    a[2] += __builtin_bit_cast(f32x2, u);
    u.x = p.w << 16; u.y = p.w & 0xFFFF0000u;
    a[3] += __builtin_bit_cast(f32x2, u);
}

__global__ __launch_bounds__(512) void k_fused(const int2* __restrict__ node_pm,
                                               const int* __restrict__ gid_pad,
                                               const unsigned short* __restrict__ xb,
                                               const unsigned short* __restrict__ Wf,
                                               const float* __restrict__ bias,
                                               const unsigned short* __restrict__ Wsf,
                                               const float* __restrict__ bssl,
                                               unsigned short* __restrict__ out_bf,
                                               float* __restrict__ out_f32,
                                               float* __restrict__ ssl_out) {
    __shared__ __align__(16) unsigned short Atile[32 * AROW];   // 33280 B
    int tid = threadIdx.x;
    int wave = tid >> 6, lane = tid & 63;
    int node_base = blockIdx.x * 32;
    int tl = lane >> 3, fo = lane & 7;
    const uint4* xs = (const uint4*)xb;         // row gid -> uint4 index gid*8 + fo

    int2 pm[4];
#pragma unroll
    for (int i = 0; i < 4; ++i) pm[i] = node_pm[node_base + wave * 4 + i];

    int pb[4], ml[4];
    const int* gp[4];
#pragma unroll
    for (int i = 0; i < 4; ++i) {
        pb[i] = __builtin_amdgcn_readfirstlane(pm[i].x);
        ml[i] = __builtin_amdgcn_readfirstlane(pm[i].y);   // mult of 4, >= 8
        gp[i] = gid_pad + pb[i] + tl * ml[i];
    }
    // all 4 nodes' first 8 gids up front (8 independent dwordx4)
    int4 ga[4], gb[4];
#pragma unroll
    for (int i = 0; i < 4; ++i) {
        ga[i] = *(const int4*)(gp[i]);
        gb[i] = *(const int4*)(gp[i] + 4);
    }

#pragma unroll
    for (int pr = 0; pr < 2; ++pr) {
        int i0 = pr * 2, i1 = i0 + 1;
        // 16 independent gathers in flight
        uint4 p0 = xs[((unsigned)ga[i0].x << 3) + fo];
        uint4 p1 = xs[((unsigned)ga[i0].y << 3) + fo];
        uint4 p2 = xs[((unsigned)ga[i0].z << 3) + fo];
        uint4 p3 = xs[((unsigned)ga[i0].w << 3) + fo];
        uint4 p4 = xs[((unsigned)gb[i0].x << 3) + fo];
        uint4 p5 = xs[((unsigned)gb[i0].y << 3) + fo];
        uint4 p6 = xs[((unsigned)gb[i0].z << 3) + fo];
        uint4 p7 = xs[((unsigned)gb[i0].w << 3) + fo];
        uint4 q0 = xs[((unsigned)ga[i1].x << 3) + fo];
        uint4 q1 = xs[((unsigned)ga[i1].y << 3) + fo];
        uint4 q2 = xs[((unsigned)ga[i1].z << 3) + fo];
        uint4 q3 = xs[((unsigned)ga[i1].w << 3) + fo];
        uint4 q4 = xs[((unsigned)gb[i1].x << 3) + fo];
        uint4 q5 = xs[((unsigned)gb[i1].y << 3) + fo];
        uint4 q6 = xs[((unsigned)gb[i1].z << 3) + fo];
        uint4 q7 = xs[((unsigned)gb[i1].w << 3) + fo];
        f32x2 a0[4] = {{0.f,0.f},{0.f,0.f},{0.f,0.f},{0.f,0.f}};
        f32x2 a1[4] = {{0.f,0.f},{0.f,0.f},{0.f,0.f},{0.f,0.f}};
        accumP(a0, p0); accumP(a0, p1); accumP(a0, p2); accumP(a0, p3);
        accumP(a0, p4); accumP(a0, p5); accumP(a0, p6); accumP(a0, p7);
        accumP(a1, q0); accumP(a1, q1); accumP(a1, q2); accumP(a1, q3);
        accumP(a1, q4); accumP(a1, q5); accumP(a1, q6); accumP(a1, q7);
        // rare tails (ml > 8; ~16% of nodes), step 4
#pragma unroll 1
        for (int k = 8; k < ml[i0]; k += 4) {
            int4 g = *(const int4*)(gp[i0] + k);
            uint4 t0 = xs[((unsigned)g.x << 3) + fo];
            uint4 t1 = xs[((unsigned)g.y << 3) + fo];
            uint4 t2 = xs[((unsigned)g.z << 3) + fo];
            uint4 t3 = xs[((unsigned)g.w << 3) + fo];
            accumP(a0, t0); accumP(a0, t1); accumP(a0, t2); accumP(a0, t3);
        }
#pragma unroll 1
        for (int k = 8; k < ml[i1]; k += 4) {
            int4 g = *(const int4*)(gp[i1] + k);
            uint4 t0 = xs[((unsigned)g.x << 3) + fo];
            uint4 t1 = xs[((unsigned)g.y << 3) + fo];
            uint4 t2 = xs[((unsigned)g.z << 3) + fo];
            uint4 t3 = xs[((unsigned)g.w << 3) + fo];
            accumP(a1, t0); accumP(a1, t1); accumP(a1, t2); accumP(a1, t3);
        }
        // pack 8 f32 -> 8 bf16 (HW packed cvt, RTNE), one b128 LDS store per node.
        unsigned r0, r1, r2, r3;
        asm("v_cvt_pk_bf16_f32 %0, %1, %2" : "=v"(r0) : "v"(a0[0].x), "v"(a0[0].y));
        asm("v_cvt_pk_bf16_f32 %0, %1, %2" : "=v"(r1) : "v"(a0[1].x), "v"(a0[1].y));
        asm("v_cvt_pk_bf16_f32 %0, %1, %2" : "=v"(r2) : "v"(a0[2].x), "v"(a0[2].y));
        asm("v_cvt_pk_bf16_f32 %0, %1, %2" : "=v"(r3) : "v"(a0[3].x), "v"(a0[3].y));
        uint4 st; st.x = r0; st.y = r1; st.z = r2; st.w = r3;
        *(uint4*)(&Atile[(wave * 4 + i0) * AROW + tl * 64 + fo * 8]) = st;
        asm("v_cvt_pk_bf16_f32 %0, %1, %2" : "=v"(r0) : "v"(a1[0].x), "v"(a1[0].y));
        asm("v_cvt_pk_bf16_f32 %0, %1, %2" : "=v"(r1) : "v"(a1[1].x), "v"(a1[1].y));
        asm("v_cvt_pk_bf16_f32 %0, %1, %2" : "=v"(r2) : "v"(a1[2].x), "v"(a1[2].y));
        asm("v_cvt_pk_bf16_f32 %0, %1, %2" : "=v"(r3) : "v"(a1[3].x), "v"(a1[3].y));
        st.x = r0; st.y = r1; st.z = r2; st.w = r3;
        *(uint4*)(&Atile[(wave * 4 + i1) * AROW + tl * 64 + fo * 8]) = st;
    }
    __syncthreads();

    // GEMM: wave -> (node-tile nt = wave>>2, col-tile c = wave&3), 16 MFMA
    int nt = wave >> 2, c = wave & 3;
    int m = lane & 15, q = lane >> 4;
    floatx4 acc = (floatx4){0.f, 0.f, 0.f, 0.f};
    const short8* wf8 = (const short8*)Wf;
    const unsigned short* abase = &Atile[(nt * 16 + m) * AROW + q * 8];
#pragma unroll
    for (int ks = 0; ks < 16; ++ks) {
        short8 a = *(const short8*)(abase + ks * 32);
        short8 b = wf8[(c * 16 + ks) * 64 + lane];
        acc = __builtin_amdgcn_mfma_f32_16x16x32_bf16(a, b, acc, 0, 0, 0);
    }
    float bb = bias[c * 16 + m];
    int node0 = node_base + nt * 16;
    float vv[4];
#pragma unroll
    for (int i = 0; i < 4; ++i) {
        float v = acc[i] + bb;
        vv[i] = v > 0.f ? v : 0.f;
        int node = node0 + q * 4 + i;                 // C/D: row = quad*4 + reg
        size_t idx = (size_t)node * 64 + c * 16 + m;  //      col = lane&15
        if (out_bf)  out_bf[idx] = f2bf(vv[i]);
        if (out_f32) out_f32[idx] = vv[i];
    }

    // ---- fused SSL: ssl = h2[32x64] @ Wssl[64x64] + bssl, h2 block-resident ----
    if (ssl_out) {
        __syncthreads();                          // Atile reads complete; safe to alias
        unsigned short* Ht = Atile;               // h2 tile, pitch HROW shorts
#pragma unroll
        for (int i = 0; i < 4; ++i) {
            int nl = nt * 16 + q * 4 + i;         // 0..31 within block
            Ht[nl * HROW + c * 16 + m] = f2bf(vv[i]);
        }
        __syncthreads();
        int nt2 = wave >> 2, c2 = wave & 3;       // 2 node-tiles x 4 col-tiles = 8 waves
        floatx4 sacc = (floatx4){0.f, 0.f, 0.f, 0.f};
        const short8* sw8 = (const short8*)Wsf;
        const unsigned short* sab = &Ht[(nt2 * 16 + m) * HROW + q * 8];
#pragma unroll
        for (int ks = 0; ks < 2; ++ks) {
            short8 a = *(const short8*)(sab + ks * 32);
            short8 b = sw8[(c2 * 2 + ks) * 64 + lane];
            sacc = __builtin_amdgcn_mfma_f32_16x16x32_bf16(a, b, sacc, 0, 0, 0);
        }
        float sb = bssl[c2 * 16 + m];
        int n0 = node_base + nt2 * 16;
#pragma unroll
        for (int i = 0; i < 4; ++i) {
            int node = n0 + q * 4 + i;
            ssl_out[(size_t)node * 64 + c2 * 16 + m] = sacc[i] + sb;
        }
    }
}

// ---------------- launch ----------------

extern "C" void kernel_launch(void* const* d_in, const int* in_sizes, int n_in,
                              void* d_out, int out_size, void* d_ws, size_t ws_size,
                              hipStream_t stream) {
    const float* x    = (const float*)d_in[0];
    const int*   ei   = (const int*)d_in[1];   // [2,E]: row0 src, row1 dst
    const int*   ti   = (const int*)d_in[2];
    const float* W1   = (const float*)d_in[3];
    const float* b1   = (const float*)d_in[4];
    const float* W2   = (const float*)d_in[5];
    const float* b2   = (const float*)d_in[6];
    const float* Wssl = (const float*)d_in[7];
    const float* bssl = (const float*)d_in[8];
    float* out = (float*)d_out;

    char* w = (char*)d_ws;
    auto alloc = [&](size_t bytes) -> char* {
        char* p = w;
        w += (bytes + 255) & ~(size_t)255;
        return p;
    };
    int* cursor   = (int*)alloc((size_t)NBP * 4);
    unsigned int* words = (unsigned int*)alloc((size_t)NB * CAP * 4);
    int2* node_pm = (int2*)alloc((size_t)N_NODES * 8);
    int* gid_pad  = (int*)alloc((size_t)NB * PCAP * 4);
    unsigned short* xb  = (unsigned short*)alloc((size_t)(N_NODES + 1) * 64 * 2);
    unsigned short* h1b = (unsigned short*)alloc((size_t)(N_NODES + 1) * 64 * 2);
    unsigned short* Wf1 = (unsigned short*)alloc((size_t)512 * 64 * 2);
    unsigned short* Wf2 = (unsigned short*)alloc((size_t)512 * 64 * 2);
    unsigned short* Wsf = (unsigned short*)alloc((size_t)64 * 64 * 2);

    hipMemsetAsync(cursor, 0, (size_t)NBP * 4, stream);
    k_bscatter<<<(N_EDGES + 4095) / 4096, 1024, 0, stream>>>(ei, ti, cursor, words,
                                                             x, xb, h1b, W1, W2, Wssl,
                                                             Wf1, Wf2, Wsf);
    k_lsort<<<NB, 1024, 0, stream>>>(cursor, words, node_pm, gid_pad);

    // conv1 fused: agg(xb) + GEMM W1 + relu -> h1b (bf16)
    k_fused<<<N_NODES / 32, 512, 0, stream>>>(node_pm, gid_pad, xb, Wf1, b1,
                                              nullptr, nullptr, h1b, nullptr, nullptr);
    // conv2 fused: agg(h1b) + GEMM W2 + relu -> out fp32, + fused SSL -> out+N*64
    k_fused<<<N_NODES / 32, 512, 0, stream>>>(node_pm, gid_pad, h1b, Wf2, b2,
                                              Wsf, bssl, nullptr, out,
                                              out + (size_t)N_NODES * 64);
}